// Round 2
// baseline (203.469 us; speedup 1.0000x reference)
//
#include <hip/hip_runtime.h>
#include <math.h>

#define Bsz 512
#define NA  128
#define NL  512
#define Dd  128
#define KA  16
#define KL  16

// ---------------------------------------------------------------------------
// Bool-layout detection: jax bool arrays may arrive as 1-byte bools or as
// int32 0/1. If int32, every byte at offset (i&3)!=0 is zero. Real bool
// arrays (~50% ones) have nonzero off-bytes with overwhelming probability.
// flag=1 -> 1-byte bool layout, flag=0 -> int32 layout.
// ---------------------------------------------------------------------------
__global__ __launch_bounds__(256) void detect_bool_kernel(
    const unsigned char* __restrict__ av, int* __restrict__ flag) {
  __shared__ int s;
  if (threadIdx.x == 0) s = 0;
  __syncthreads();
  int any = 0;
  for (int i = threadIdx.x; i < 4096; i += 256)
    if ((i & 3) && av[i]) any = 1;
  if (any) atomicOr(&s, 1);
  __syncthreads();
  if (threadIdx.x == 0) *flag = s;
}

__device__ __forceinline__ int validAt(const unsigned char* p, int i, int isbyte) {
  return isbyte ? (int)p[i] : ((const int*)p)[i];
}

// ---------------------------------------------------------------------------
// Kernel A: per-batch index selection (unchanged from R1 — correct).
// ---------------------------------------------------------------------------
__global__ __launch_bounds__(256) void idx_kernel(
    const float* __restrict__ spike, const unsigned char* __restrict__ avalid,
    const float* __restrict__ xc, const float* __restrict__ lc,
    const unsigned char* __restrict__ lvalid, const int* __restrict__ flagp,
    int* __restrict__ aidx, int* __restrict__ lidx) {
  const int b = blockIdx.x;
  const int tid = threadIdx.x;
  const int isbyte = *flagp;

  __shared__ float s_ax[KA], s_ay[KA];
  __shared__ int   s_ai[KA];
  __shared__ float s_ld[NL];
  __shared__ float s_rv[4];
  __shared__ int   s_ri[4];

  // ---- agent top-16: wave 0 only, 2 candidates per lane ----
  if (tid < 64) {
    float v0 = validAt(avalid, b * NA + tid, isbyte)      ? spike[b * NA + tid]      : -INFINITY;
    float v1 = validAt(avalid, b * NA + tid + 64, isbyte) ? spike[b * NA + tid + 64] : -INFINITY;
    for (int it = 0; it < KA; ++it) {
      float bv = v0; int bi = tid;
      if (v1 > bv) { bv = v1; bi = tid + 64; }   // tie keeps lower index (tid)
      for (int off = 32; off; off >>= 1) {
        float ov = __shfl_xor(bv, off);
        int   oi = __shfl_xor(bi, off);
        if (ov > bv || (ov == bv && oi < bi)) { bv = ov; bi = oi; }
      }
      if (bi == tid)      v0 = -INFINITY;
      if (bi == tid + 64) v1 = -INFINITY;
      if (tid == 0) s_ai[it] = bi;
    }
  }
  __syncthreads();
  if (tid < KA) {
    int a = s_ai[tid];
    aidx[b * KA + tid] = a;
    s_ax[tid] = xc[(b * NA + a) * 2 + 0];
    s_ay[tid] = xc[(b * NA + a) * 2 + 1];
  }
  __syncthreads();

  // ---- lane distances (min of squared dist; sqrt after, monotone) ----
  for (int l = tid; l < NL; l += 256) {
    float lx = lc[(b * NL + l) * 2 + 0];
    float ly = lc[(b * NL + l) * 2 + 1];
    float best = INFINITY;
#pragma unroll
    for (int a = 0; a < KA; ++a) {
      float dx = s_ax[a] - lx, dy = s_ay[a] - ly;
      float d2 = __fadd_rn(__fmul_rn(dx, dx), __fmul_rn(dy, dy));  // no fma contraction
      best = fminf(best, d2);
    }
    best = sqrtf(best);
    s_ld[l] = validAt(lvalid, b * NL + l, isbyte) ? best : INFINITY;
  }
  __syncthreads();

  // ---- lane top-16 smallest: block-wide iterative argmin ----
  const int wid = tid >> 6, lane = tid & 63;
  for (int it = 0; it < KL; ++it) {
    float bv = s_ld[tid]; int bi = tid;
    float v2 = s_ld[tid + 256];
    if (v2 < bv) { bv = v2; bi = tid + 256; }    // tie keeps lower index
    for (int off = 32; off; off >>= 1) {
      float ov = __shfl_xor(bv, off);
      int   oi = __shfl_xor(bi, off);
      if (ov < bv || (ov == bv && oi < bi)) { bv = ov; bi = oi; }
    }
    if (lane == 0) { s_rv[wid] = bv; s_ri[wid] = bi; }
    __syncthreads();
    if (tid == 0) {
      float fbv = s_rv[0]; int fbi = s_ri[0];
      for (int w = 1; w < 4; ++w)
        if (s_rv[w] < fbv || (s_rv[w] == fbv && s_ri[w] < fbi)) { fbv = s_rv[w]; fbi = s_ri[w]; }
      lidx[b * KL + it] = fbi;
      s_ld[fbi] = INFINITY;
    }
    __syncthreads();
  }
}

// ---------------------------------------------------------------------------
// Fused kernel: one block (512 thr) per batch.
//   waves 0-3: gather own 8 rows, 2x(residual MLP + LN) with software-
//              pipelined weight loads, scatter own rows to output.
//   waves 4-7: stream-copy the 608 unselected rows input -> output.
// No __syncthreads after index setup: MLP waves' LDS rows are wave-private.
// ---------------------------------------------------------------------------

#define LOADW(W, g, w00,w01,w02,w03,w10,w11,w12,w13)            \
  w00 = (W)[((g)*4+0)*Dd + j0]; w10 = (W)[((g)*4+0)*Dd + j1];   \
  w01 = (W)[((g)*4+1)*Dd + j0]; w11 = (W)[((g)*4+1)*Dd + j1];   \
  w02 = (W)[((g)*4+2)*Dd + j0]; w12 = (W)[((g)*4+2)*Dd + j1];   \
  w03 = (W)[((g)*4+3)*Dd + j0]; w13 = (W)[((g)*4+3)*Dd + j1];

#define FMAG(SRC, g, w00,w01,w02,w03,w10,w11,w12,w13)                         \
  _Pragma("unroll")                                                           \
  for (int n = 0; n < 8; ++n) {                                               \
    float4 xv = ((const float4*)(SRC)[n0 + n])[(g)];                          \
    acc0[n] = fmaf(xv.x, w00, acc0[n]); acc1[n] = fmaf(xv.x, w10, acc1[n]);   \
    acc0[n] = fmaf(xv.y, w01, acc0[n]); acc1[n] = fmaf(xv.y, w11, acc1[n]);   \
    acc0[n] = fmaf(xv.z, w02, acc0[n]); acc1[n] = fmaf(xv.z, w12, acc1[n]);   \
    acc0[n] = fmaf(xv.w, w03, acc0[n]); acc1[n] = fmaf(xv.w, w13, acc1[n]);   \
  }

__global__ __launch_bounds__(512, 4) void fused_kernel(
    const float* __restrict__ actor_feat, const float* __restrict__ lane_feat,
    const int* __restrict__ aidx, const int* __restrict__ lidx,
    const float* __restrict__ W0a, const float* __restrict__ b0a,
    const float* __restrict__ W0b, const float* __restrict__ b0b,
    const float* __restrict__ W1a, const float* __restrict__ b1a,
    const float* __restrict__ W1b, const float* __restrict__ b1b,
    const float* __restrict__ gamma, const float* __restrict__ beta,
    float* __restrict__ out0, float* __restrict__ out1) {
  const int b = blockIdx.x, tid = threadIdx.x;
  __shared__ float s_x[32][Dd];
  __shared__ float s_u[32][Dd];
  __shared__ int   s_src[32];
  __shared__ unsigned int s_amask[4];
  __shared__ unsigned int s_lmask[16];

  if (tid < 4) s_amask[tid] = 0u;
  if (tid >= 4 && tid < 20) s_lmask[tid - 4] = 0u;
  __syncthreads();
  if (tid < 16) {
    int a = aidx[b * KA + tid];
    s_src[tid] = a;
    atomicOr(&s_amask[a >> 5], 1u << (a & 31));
  } else if (tid < 32) {
    int l = lidx[b * KL + (tid - 16)];
    s_src[tid] = l;
    atomicOr(&s_lmask[l >> 5], 1u << (l & 31));
  }
  __syncthreads();   // last block-wide barrier: masks + s_src ready

  const int wave = tid >> 6, lane = tid & 63;

  if (wave < 4) {
    // ================= MLP role (waves 0-3, rows are wave-private) ========
    const int n0 = wave * 8;
    // gather own 8 rows: 8 x 32 float4, 64 lanes -> 4 each
    for (int q = lane; q < 256; q += 64) {
      int row = n0 + (q >> 5), c4 = q & 31;
      const float* src = (row < 16)
          ? actor_feat + ((size_t)b * NA + s_src[row]) * Dd
          : lane_feat  + ((size_t)b * NL + s_src[row]) * Dd;
      ((float4*)s_x[row])[c4] = ((const float4*)src)[c4];
    }

    const int j0 = lane, j1 = lane + 64;
    const float g0 = gamma[j0], g1 = gamma[j1];
    const float bt0 = beta[j0], bt1 = beta[j1];
    const float* WA[2] = {W0a, W1a}; const float* BA[2] = {b0a, b1a};
    const float* WB[2] = {W0b, W1b}; const float* BB[2] = {b0b, b1b};

#pragma unroll 1
    for (int layer = 0; layer < 2; ++layer) {
      const float* wa = WA[layer];
      const float* wb = WB[layer];
      float acc0[8], acc1[8];

      // ---- matvec 1: t = x @ Wa + ba (double-buffered weight prefetch) ----
      {
        const float bias0 = BA[layer][j0], bias1 = BA[layer][j1];
#pragma unroll
        for (int n = 0; n < 8; ++n) { acc0[n] = bias0; acc1[n] = bias1; }
        float a00,a01,a02,a03,a10,a11,a12,a13;
        float c00,c01,c02,c03,c10,c11,c12,c13;
        LOADW(wa, 0, a00,a01,a02,a03,a10,a11,a12,a13);
#pragma unroll 1
        for (int g = 0; g < 32; g += 2) {
          LOADW(wa, g+1, c00,c01,c02,c03,c10,c11,c12,c13);
          FMAG(s_x, g,   a00,a01,a02,a03,a10,a11,a12,a13);
          if (g + 2 < 32) { LOADW(wa, g+2, a00,a01,a02,a03,a10,a11,a12,a13); }
          FMAG(s_x, g+1, c00,c01,c02,c03,c10,c11,c12,c13);
        }
      }

      // ---- exact GELU -> s_u (own rows only) ----
#pragma unroll
      for (int n = 0; n < 8; ++n) {
        float t0 = acc0[n], t1 = acc1[n];
        s_u[n0 + n][j0] = 0.5f * t0 * (1.0f + erff(t0 * 0.70710678118654752f));
        s_u[n0 + n][j1] = 0.5f * t1 * (1.0f + erff(t1 * 0.70710678118654752f));
      }

      // ---- matvec 2: h = gelu(t) @ Wb + bb ----
      {
        const float bias0 = BB[layer][j0], bias1 = BB[layer][j1];
#pragma unroll
        for (int n = 0; n < 8; ++n) { acc0[n] = bias0; acc1[n] = bias1; }
        float a00,a01,a02,a03,a10,a11,a12,a13;
        float c00,c01,c02,c03,c10,c11,c12,c13;
        LOADW(wb, 0, a00,a01,a02,a03,a10,a11,a12,a13);
#pragma unroll 1
        for (int g = 0; g < 32; g += 2) {
          LOADW(wb, g+1, c00,c01,c02,c03,c10,c11,c12,c13);
          FMAG(s_u, g,   a00,a01,a02,a03,a10,a11,a12,a13);
          if (g + 2 < 32) { LOADW(wb, g+2, a00,a01,a02,a03,a10,a11,a12,a13); }
          FMAG(s_u, g+1, c00,c01,c02,c03,c10,c11,c12,c13);
        }
      }

      // ---- residual + LayerNorm (row across wave: 2 cols/lane) ----
#pragma unroll
      for (int n = 0; n < 8; ++n) {
        float r0 = s_x[n0 + n][j0] + acc0[n];
        float r1 = s_x[n0 + n][j1] + acc1[n];
        float sum = r0 + r1;
        for (int off = 32; off; off >>= 1) sum += __shfl_xor(sum, off);
        float mean = sum * (1.0f / 128.0f);
        float d0 = r0 - mean, d1 = r1 - mean;
        float sq = d0 * d0 + d1 * d1;
        for (int off = 32; off; off >>= 1) sq += __shfl_xor(sq, off);
        float inv = 1.0f / sqrtf(sq * (1.0f / 128.0f) + 1e-5f);
        float v0 = d0 * inv * g0 + bt0;
        float v1 = d1 * inv * g1 + bt1;
        if (layer == 0) {
          s_x[n0 + n][j0] = v0;
          s_x[n0 + n][j1] = v1;
        } else {
          // scatter directly from registers
          int row = n0 + n, sidx = s_src[row];
          float* dst = (row < 16) ? out0 + ((size_t)b * NA + sidx) * Dd
                                  : out1 + ((size_t)b * NL + sidx) * Dd;
          dst[j0] = v0;
          dst[j1] = v1;
        }
      }
    }
  } else {
    // ================= copy role (waves 4-7): 608 unselected rows =========
    const int cw = wave - 4;
    const int rbeg = cw * 160;                 // 4 waves x 160 rows = 640
#pragma unroll 1
    for (int r = rbeg; r < rbeg + 160; r += 4) {
      float2 v[4]; bool sk[4];
      const float2* sp[4]; float2* dp[4];
#pragma unroll
      for (int u = 0; u < 4; ++u) {
        int rr = r + u;
        if (rr < NA) {
          sk[u] = (s_amask[rr >> 5] >> (rr & 31)) & 1u;
          sp[u] = (const float2*)(actor_feat + ((size_t)b * NA + rr) * Dd);
          dp[u] = (float2*)(out0 + ((size_t)b * NA + rr) * Dd);
        } else {
          int l = rr - NA;
          sk[u] = (s_lmask[l >> 5] >> (l & 31)) & 1u;
          sp[u] = (const float2*)(lane_feat + ((size_t)b * NL + l) * Dd);
          dp[u] = (float2*)(out1 + ((size_t)b * NL + l) * Dd);
        }
        if (!sk[u]) v[u] = sp[u][lane];        // 4 HBM loads in flight
      }
#pragma unroll
      for (int u = 0; u < 4; ++u)
        if (!sk[u]) dp[u][lane] = v[u];
    }
  }
}

// ---------------------------------------------------------------------------
extern "C" void kernel_launch(void* const* d_in, const int* in_sizes, int n_in,
                              void* d_out, int out_size, void* d_ws, size_t ws_size,
                              hipStream_t stream) {
  const float* actor_feat = (const float*)d_in[0];
  const float* lane_feat  = (const float*)d_in[1];
  const float* lc         = (const float*)d_in[2];
  const float* xc         = (const float*)d_in[3];
  const float* spike      = (const float*)d_in[4];
  const unsigned char* avalid = (const unsigned char*)d_in[5];
  const unsigned char* lvalid = (const unsigned char*)d_in[6];
  const float* W0a = (const float*)d_in[7];
  const float* b0a = (const float*)d_in[8];
  const float* W0b = (const float*)d_in[9];
  const float* b0b = (const float*)d_in[10];
  const float* W1a = (const float*)d_in[11];
  const float* b1a = (const float*)d_in[12];
  const float* W1b = (const float*)d_in[13];
  const float* b1b = (const float*)d_in[14];
  const float* gamma = (const float*)d_in[15];
  const float* beta  = (const float*)d_in[16];

  int* aidx = (int*)d_ws;
  int* lidx = aidx + Bsz * KA;
  int* flag = lidx + Bsz * KL;

  float* out0 = (float*)d_out;
  float* out1 = out0 + (size_t)Bsz * NA * Dd;

  detect_bool_kernel<<<1, 256, 0, stream>>>(avalid, flag);
  idx_kernel<<<Bsz, 256, 0, stream>>>(spike, avalid, xc, lc, lvalid, flag, aidx, lidx);
  fused_kernel<<<Bsz, 512, 0, stream>>>(actor_feat, lane_feat, aidx, lidx,
                                        W0a, b0a, W0b, b0b, W1a, b1a, W1b, b1b,
                                        gamma, beta, out0, out1);
}

// Round 4
// 122.290 us; speedup vs baseline: 1.6638x; 1.6638x over previous
//
#include <hip/hip_runtime.h>
#include <math.h>

#define Bsz 512
#define NA  128
#define NL  512
#define Dd  128
#define KA  16
#define KL  16

#define NMLP  256        // MLP blocks: 2 batches each
#define NCOPY 1280       // copy blocks
#define PAIRS (Bsz * 320) // 640 rows/batch -> 320 row-pairs

// ws layout (int offsets)
#define AIDX_OFF  0
#define LIDX_OFF  8192
#define AMASK_OFF 16384
#define LMASK_OFF 18432
#define FLAG_OFF  26624

typedef float nf4 __attribute__((ext_vector_type(4)));  // native vec for nontemporal builtins

// ---------------------------------------------------------------------------
// Bool-layout detection (jax bool may arrive as 1-byte or int32 0/1).
// ---------------------------------------------------------------------------
__global__ __launch_bounds__(256) void detect_bool_kernel(
    const unsigned char* __restrict__ av, int* __restrict__ flag) {
  __shared__ int s;
  if (threadIdx.x == 0) s = 0;
  __syncthreads();
  int any = 0;
  for (int i = threadIdx.x; i < 4096; i += 256)
    if ((i & 3) && av[i]) any = 1;
  if (any) atomicOr(&s, 1);
  __syncthreads();
  if (threadIdx.x == 0) *flag = s;
}

__device__ __forceinline__ int validAt(const unsigned char* p, int i, int isbyte) {
  return isbyte ? (int)p[i] : ((const int*)p)[i];
}

// ---------------------------------------------------------------------------
// Kernel A: per-batch index selection + selected-row bitmasks.
// ---------------------------------------------------------------------------
__global__ __launch_bounds__(256) void idx_kernel(
    const float* __restrict__ spike, const unsigned char* __restrict__ avalid,
    const float* __restrict__ xc, const float* __restrict__ lc,
    const unsigned char* __restrict__ lvalid, const int* __restrict__ flagp,
    int* __restrict__ aidx, int* __restrict__ lidx,
    unsigned* __restrict__ amask_g, unsigned* __restrict__ lmask_g) {
  const int b = blockIdx.x;
  const int tid = threadIdx.x;
  const int isbyte = *flagp;

  __shared__ float s_ax[KA], s_ay[KA];
  __shared__ int   s_ai[KA];
  __shared__ int   s_li[KL];
  __shared__ float s_ld[NL];
  __shared__ float s_rv[4];
  __shared__ int   s_ri[4];
  __shared__ unsigned s_am[4], s_lm[16];

  // ---- agent top-16: wave 0 only, 2 candidates per lane ----
  if (tid < 64) {
    float v0 = validAt(avalid, b * NA + tid, isbyte)      ? spike[b * NA + tid]      : -INFINITY;
    float v1 = validAt(avalid, b * NA + tid + 64, isbyte) ? spike[b * NA + tid + 64] : -INFINITY;
    for (int it = 0; it < KA; ++it) {
      float bv = v0; int bi = tid;
      if (v1 > bv) { bv = v1; bi = tid + 64; }   // tie keeps lower index
      for (int off = 32; off; off >>= 1) {
        float ov = __shfl_xor(bv, off);
        int   oi = __shfl_xor(bi, off);
        if (ov > bv || (ov == bv && oi < bi)) { bv = ov; bi = oi; }
      }
      if (bi == tid)      v0 = -INFINITY;
      if (bi == tid + 64) v1 = -INFINITY;
      if (tid == 0) s_ai[it] = bi;
    }
  }
  __syncthreads();
  if (tid < KA) {
    int a = s_ai[tid];
    aidx[b * KA + tid] = a;
    s_ax[tid] = xc[(b * NA + a) * 2 + 0];
    s_ay[tid] = xc[(b * NA + a) * 2 + 1];
  }
  __syncthreads();

  // ---- lane distances (min of squared dist; sqrt after, monotone) ----
  for (int l = tid; l < NL; l += 256) {
    float lx = lc[(b * NL + l) * 2 + 0];
    float ly = lc[(b * NL + l) * 2 + 1];
    float best = INFINITY;
#pragma unroll
    for (int a = 0; a < KA; ++a) {
      float dx = s_ax[a] - lx, dy = s_ay[a] - ly;
      float d2 = __fadd_rn(__fmul_rn(dx, dx), __fmul_rn(dy, dy));  // no fma contraction
      best = fminf(best, d2);
    }
    best = sqrtf(best);
    s_ld[l] = validAt(lvalid, b * NL + l, isbyte) ? best : INFINITY;
  }
  __syncthreads();

  // ---- lane top-16 smallest: block-wide iterative argmin ----
  const int wid = tid >> 6, lane = tid & 63;
  for (int it = 0; it < KL; ++it) {
    float bv = s_ld[tid]; int bi = tid;
    float v2 = s_ld[tid + 256];
    if (v2 < bv) { bv = v2; bi = tid + 256; }
    for (int off = 32; off; off >>= 1) {
      float ov = __shfl_xor(bv, off);
      int   oi = __shfl_xor(bi, off);
      if (ov < bv || (ov == bv && oi < bi)) { bv = ov; bi = oi; }
    }
    if (lane == 0) { s_rv[wid] = bv; s_ri[wid] = bi; }
    __syncthreads();
    if (tid == 0) {
      float fbv = s_rv[0]; int fbi = s_ri[0];
      for (int w = 1; w < 4; ++w)
        if (s_rv[w] < fbv || (s_rv[w] == fbv && s_ri[w] < fbi)) { fbv = s_rv[w]; fbi = s_ri[w]; }
      lidx[b * KL + it] = fbi;
      s_li[it] = fbi;
      s_ld[fbi] = INFINITY;
    }
    __syncthreads();
  }

  // ---- selected-row bitmasks (per batch; deterministic, no global atomics) --
  if (tid < 4)  s_am[tid] = 0u;
  if (tid < 16) s_lm[tid] = 0u;
  __syncthreads();
  if (tid < 16) {
    int a = s_ai[tid];
    atomicOr(&s_am[a >> 5], 1u << (a & 31));
  } else if (tid < 32) {
    int l = s_li[tid - 16];
    atomicOr(&s_lm[l >> 5], 1u << (l & 31));
  }
  __syncthreads();
  if (tid < 4)  amask_g[b * 4 + tid]  = s_am[tid];
  if (tid < 16) lmask_g[b * 16 + tid] = s_lm[tid];
}

// ---------------------------------------------------------------------------
// Fused kernel, role by blockIdx:
//   blocks [0, NMLP):      MLP for 2 batches, weights LDS-staged per half.
//   blocks [NMLP, +NCOPY): nontemporal stream-copy of unselected rows.
// ---------------------------------------------------------------------------

#define STAGE_LOAD(W, h)                                              \
  { const float4* wg4 = (const float4*)((W) + (h) * 8192);            \
    R0 = wg4[tid]; R1 = wg4[512 + tid];                               \
    R2 = wg4[1024 + tid]; R3 = wg4[1536 + tid]; }

#define STAGE_WRITE()                                                 \
  { float4* swg4 = (float4*)s_w;                                      \
    swg4[tid] = R0; swg4[512 + tid] = R1;                             \
    swg4[1024 + tid] = R2; swg4[1536 + tid] = R3; }

#define FMA_HALF(h)                                                   \
  _Pragma("unroll 4")                                                 \
  for (int g = 0; g < 16; ++g) {                                      \
    const float* wr = s_w + g * 4 * Dd;                               \
    float w00 = wr[j0],        w10 = wr[j1];                          \
    float w01 = wr[Dd + j0],   w11 = wr[Dd + j1];                     \
    float w02 = wr[2*Dd + j0], w12 = wr[2*Dd + j1];                   \
    float w03 = wr[3*Dd + j0], w13 = wr[3*Dd + j1];                   \
    _Pragma("unroll")                                                 \
    for (int n = 0; n < 8; ++n) {                                     \
      float4 xv = ((const float4*)s_xu[n0 + n])[(h) * 16 + g];        \
      acc0[n] = fmaf(xv.x, w00, acc0[n]); acc1[n] = fmaf(xv.x, w10, acc1[n]); \
      acc0[n] = fmaf(xv.y, w01, acc0[n]); acc1[n] = fmaf(xv.y, w11, acc1[n]); \
      acc0[n] = fmaf(xv.z, w02, acc0[n]); acc1[n] = fmaf(xv.z, w12, acc1[n]); \
      acc0[n] = fmaf(xv.w, w03, acc0[n]); acc1[n] = fmaf(xv.w, w13, acc1[n]); \
    }                                                                 \
  }

// staging: load h0; write; sync; prefetch h1 under FMA(h0); sync; write; sync;
// FMA(h1); sync (s_w free for next matvec)
#define MATVEC(W, Bv)                                                 \
  { const float bias0 = (Bv)[j0], bias1 = (Bv)[j1];                   \
    _Pragma("unroll")                                                 \
    for (int n = 0; n < 8; ++n) { acc0[n] = bias0; acc1[n] = bias1; } \
    STAGE_LOAD(W, 0);                                                 \
    STAGE_WRITE(); __syncthreads();                                   \
    STAGE_LOAD(W, 1);                                                 \
    FMA_HALF(0);                                                      \
    __syncthreads();                                                  \
    STAGE_WRITE(); __syncthreads();                                   \
    FMA_HALF(1);                                                      \
    __syncthreads(); }

__global__ __launch_bounds__(512, 4) void fused_kernel(
    const float* __restrict__ actor_feat, const float* __restrict__ lane_feat,
    const int* __restrict__ aidx, const int* __restrict__ lidx,
    const unsigned* __restrict__ amask_g, const unsigned* __restrict__ lmask_g,
    const float* __restrict__ W0a, const float* __restrict__ b0a,
    const float* __restrict__ W0b, const float* __restrict__ b0b,
    const float* __restrict__ W1a, const float* __restrict__ b1a,
    const float* __restrict__ W1b, const float* __restrict__ b1b,
    const float* __restrict__ gamma, const float* __restrict__ beta,
    float* __restrict__ out0, float* __restrict__ out1) {
  __shared__ float s_w[64 * Dd];      // 32 KB: half weight matrix
  __shared__ float s_xu[64][Dd];      // 32 KB: 2 batches x 32 rows (x, then u)
  __shared__ int   s_src[64];

  const int tid = threadIdx.x;
  const int wave = tid >> 6, lane = tid & 63;

  if (blockIdx.x < NMLP) {
    // ===================== MLP role: batches b0, b0+1 =====================
    const int b0 = blockIdx.x * 2;
    if (tid < 64) {
      int rr = tid, bidx = b0 + (rr >> 5), lr = rr & 31;
      s_src[rr] = (lr < 16) ? aidx[bidx * KA + lr] : lidx[bidx * KL + lr - 16];
    }
    __syncthreads();

    const int n0 = wave * 8;
    // gather own 8 rows (wave-private thereafter)
#pragma unroll
    for (int i = 0; i < 4; ++i) {
      int q = lane + 64 * i;
      int rr = n0 + (q >> 5), c4 = q & 31;
      int bidx = b0 + (rr >> 5), lr = rr & 31;
      const float* src = (lr < 16)
          ? actor_feat + ((size_t)bidx * NA + s_src[rr]) * Dd
          : lane_feat  + ((size_t)bidx * NL + s_src[rr]) * Dd;
      ((float4*)s_xu[rr])[c4] = ((const float4*)src)[c4];
    }

    const int j0 = lane, j1 = lane + 64;
    const float g0 = gamma[j0], g1 = gamma[j1];
    const float bt0 = beta[j0], bt1 = beta[j1];

    float acc0[8], acc1[8], rx0[8], rx1[8];
    float4 R0, R1, R2, R3;

    // residual base for layer 0 (own rows, own-wave writes -> program order)
#pragma unroll
    for (int n = 0; n < 8; ++n) {
      rx0[n] = s_xu[n0 + n][j0];
      rx1[n] = s_xu[n0 + n][j1];
    }

#pragma unroll 1
    for (int layer = 0; layer < 2; ++layer) {
      const float* wa = layer ? W1a : W0a;
      const float* ba = layer ? b1a : b0a;
      const float* wb = layer ? W1b : W0b;
      const float* bb = layer ? b1b : b0b;

      // ---- t = x @ Wa + ba ----
      MATVEC(wa, ba);

      // ---- exact GELU -> overwrite own s_xu rows with u ----
#pragma unroll
      for (int n = 0; n < 8; ++n) {
        float t0 = acc0[n], t1 = acc1[n];
        s_xu[n0 + n][j0] = 0.5f * t0 * (1.0f + erff(t0 * 0.70710678118654752f));
        s_xu[n0 + n][j1] = 0.5f * t1 * (1.0f + erff(t1 * 0.70710678118654752f));
      }

      // ---- h = gelu(t) @ Wb + bb ----
      MATVEC(wb, bb);

      // ---- residual + LayerNorm ----
#pragma unroll
      for (int n = 0; n < 8; ++n) {
        float r0 = rx0[n] + acc0[n];
        float r1 = rx1[n] + acc1[n];
        float sum = r0 + r1;
        for (int off = 32; off; off >>= 1) sum += __shfl_xor(sum, off);
        float mean = sum * (1.0f / 128.0f);
        float d0 = r0 - mean, d1 = r1 - mean;
        float sq = d0 * d0 + d1 * d1;
        for (int off = 32; off; off >>= 1) sq += __shfl_xor(sq, off);
        float inv = 1.0f / sqrtf(sq * (1.0f / 128.0f) + 1e-5f);
        float v0 = d0 * inv * g0 + bt0;
        float v1 = d1 * inv * g1 + bt1;
        if (layer == 0) {
          s_xu[n0 + n][j0] = v0; s_xu[n0 + n][j1] = v1;   // layer-1 input
          rx0[n] = v0; rx1[n] = v1;                       // layer-1 residual
        } else {
          int rr = n0 + n, bidx = b0 + (rr >> 5), lr = rr & 31, si = s_src[rr];
          float* dst = (lr < 16) ? out0 + ((size_t)bidx * NA + si) * Dd
                                 : out1 + ((size_t)bidx * NL + si) * Dd;
          dst[j0] = v0;
          dst[j1] = v1;
        }
      }
    }
  } else {
    // ===================== copy role: nontemporal streaming ===============
    const int gw = (blockIdx.x - NMLP) * 8 + wave;      // 0 .. NCOPY*8-1
    const int half = lane >> 5, c4 = lane & 31;
#pragma unroll 1
    for (int base = gw * 4; base < PAIRS; base += NCOPY * 8 * 4) {
      nf4 v[4]; int sel[4];
      const nf4* sp[4]; nf4* dp[4];
#pragma unroll
      for (int u = 0; u < 4; ++u) {
        int p = base + u;
        sel[u] = 1; sp[u] = 0; dp[u] = 0;
        if (p < PAIRS) {
          int b = p / 320;
          int pr = p - b * 320;
          int r = 2 * pr + half;              // 0..639
          unsigned mword; size_t prow;
          const float* srcpool; float* dstpool; int rbit;
          if (r < NA) {
            rbit = r;
            mword = amask_g[b * 4 + (r >> 5)];
            prow = (size_t)b * NA + r;
            srcpool = actor_feat; dstpool = out0;
          } else {
            int rl = r - NA;
            rbit = rl;
            mword = lmask_g[b * 16 + (rl >> 5)];
            prow = (size_t)b * NL + rl;
            srcpool = lane_feat; dstpool = out1;
          }
          sel[u] = (mword >> (rbit & 31)) & 1;
          sp[u] = (const nf4*)(srcpool + prow * Dd) + c4;
          dp[u] = (nf4*)(dstpool + prow * Dd) + c4;
          if (!sel[u]) v[u] = __builtin_nontemporal_load(sp[u]);
        }
      }
#pragma unroll
      for (int u = 0; u < 4; ++u)
        if (!sel[u]) __builtin_nontemporal_store(v[u], dp[u]);
    }
  }
}

// ---------------------------------------------------------------------------
extern "C" void kernel_launch(void* const* d_in, const int* in_sizes, int n_in,
                              void* d_out, int out_size, void* d_ws, size_t ws_size,
                              hipStream_t stream) {
  const float* actor_feat = (const float*)d_in[0];
  const float* lane_feat  = (const float*)d_in[1];
  const float* lc         = (const float*)d_in[2];
  const float* xc         = (const float*)d_in[3];
  const float* spike      = (const float*)d_in[4];
  const unsigned char* avalid = (const unsigned char*)d_in[5];
  const unsigned char* lvalid = (const unsigned char*)d_in[6];
  const float* W0a = (const float*)d_in[7];
  const float* b0a = (const float*)d_in[8];
  const float* W0b = (const float*)d_in[9];
  const float* b0b = (const float*)d_in[10];
  const float* W1a = (const float*)d_in[11];
  const float* b1a = (const float*)d_in[12];
  const float* W1b = (const float*)d_in[13];
  const float* b1b = (const float*)d_in[14];
  const float* gamma = (const float*)d_in[15];
  const float* beta  = (const float*)d_in[16];

  int* wsI = (int*)d_ws;
  int* aidx = wsI + AIDX_OFF;
  int* lidx = wsI + LIDX_OFF;
  unsigned* amask_g = (unsigned*)(wsI + AMASK_OFF);
  unsigned* lmask_g = (unsigned*)(wsI + LMASK_OFF);
  int* flag = wsI + FLAG_OFF;

  float* out0 = (float*)d_out;
  float* out1 = out0 + (size_t)Bsz * NA * Dd;

  detect_bool_kernel<<<1, 256, 0, stream>>>(avalid, flag);
  idx_kernel<<<Bsz, 256, 0, stream>>>(spike, avalid, xc, lc, lvalid, flag,
                                      aidx, lidx, amask_g, lmask_g);
  fused_kernel<<<NMLP + NCOPY, 512, 0, stream>>>(
      actor_feat, lane_feat, aidx, lidx, amask_g, lmask_g,
      W0a, b0a, W0b, b0b, W1a, b1a, W1b, b1b, gamma, beta, out0, out1);
}